// Round 10
// baseline (1979.426 us; speedup 1.0000x reference)
//
#include <hip/hip_runtime.h>
#include <cstdint>
#include <cstddef>

// APPNP: h0 = relu(x@W1+b1)@W2+b2 ; 10x { h = 0.9*A_hat h + 0.1*h0 } ; log_softmax
// N=100000, E=3200000, F=512, H=256, C=64
// R10: L2-blocked prop. Evidence: prop unroll 8->16 in-flight changed nothing
//      (R8->R9), so prop is aggregate-bound: 422 MB/iter random gathers from a
//      12.8MB table -> ~30% L2 hit, ~290MB/iter from L3 at ~4 TB/s random rate.
//      Split src into 4 buckets of 3.2MB (<4MB XCD L2); bucketed CSR; 4
//      sequential passes/iter; f16 partial acc in the output buffer (error
//      scaled by A=0.9/deg -> ~5e-5, negligible). MLP unchanged from R9.
// ws ~58 MB (R2 passed at 65; R1 failed at ~104).

typedef _Float16 half8 __attribute__((ext_vector_type(8)));
typedef float floatx4 __attribute__((ext_vector_type(4)));

__device__ inline float2 unpack2(uint u) {
    union { uint u; _Float16 h[2]; } c; c.u = u;
    return make_float2((float)c.h[0], (float)c.h[1]);
}
__device__ inline uint pack2(float a, float b) {
    union { uint u; _Float16 h[2]; } c; c.h[0] = (_Float16)a; c.h[1] = (_Float16)b;
    return c.u;
}

// ---- W1 [512][256] f32 -> frag-contiguous f16:
//      W1tc[((kt*16 + ctile)*16 + col)*32 + j] = W1[(kt*32+j)*256 + ctile*16+col]
__global__ void transpose_w1c(const float* __restrict__ W1, _Float16* __restrict__ W1tc) {
    int i = blockIdx.x * 256 + threadIdx.x;
    if (i < 512 * 256) {
        int kt = i >> 13, ctile = (i >> 9) & 15, col = (i >> 5) & 15, j = i & 31;
        W1tc[i] = (_Float16)W1[(size_t)(kt * 32 + j) * 256 + ctile * 16 + col];
    }
}
__global__ void transpose_w2c(const float* __restrict__ W2, _Float16* __restrict__ W2tc) {
    int i = blockIdx.x * 256 + threadIdx.x;
    if (i < 256 * 64) {
        int kt = i >> 11, ct = (i >> 9) & 3, col = (i >> 5) & 15, j = i & 31;
        W2tc[i] = (_Float16)W2[(size_t)(kt * 32 + j) * 64 + ct * 16 + col];
    }
}

// ---------------- fused 2-layer MLP via f16 MFMA (unchanged from R9) ----------------
__global__ __launch_bounds__(256) void mlp_kernel(
    const float* __restrict__ x, const _Float16* __restrict__ W1tc,
    const float* __restrict__ b1, const _Float16* __restrict__ W2tc,
    const float* __restrict__ b2, const float* __restrict__ dinv,
    _Float16* __restrict__ g0h, int n)
{
    __shared__ __align__(16) _Float16 xs[32][520];
    __shared__ __align__(16) _Float16 hmid[32][264];

    const int tid  = threadIdx.x;
    const int lane = tid & 63;
    const int wid  = tid >> 6;
    const int r0blk = blockIdx.x * 32;
    const int lr = lane & 15;
    const int lg = lane >> 4;

    for (int fi = tid; fi < 32 * 128; fi += 256) {
        int r = fi >> 7, k4 = (fi & 127) * 4;
        float4 v = *(const float4*)(x + (size_t)(r0blk + r) * 512 + k4);
        union { short4 s; _Float16 h[4]; } c;
        c.h[0] = (_Float16)v.x; c.h[1] = (_Float16)v.y;
        c.h[2] = (_Float16)v.z; c.h[3] = (_Float16)v.w;
        *(short4*)&xs[r][k4] = c.s;
    }
    __syncthreads();

    floatx4 acc1[2][4];
#pragma unroll
    for (int c = 0; c < 4; ++c) {
        float b = b1[wid * 64 + c * 16 + lr];
        acc1[0][c] = (floatx4){b, b, b, b};
        acc1[1][c] = (floatx4){b, b, b, b};
    }

#pragma unroll 2
    for (int kt = 0; kt < 16; ++kt) {
        half8 bf[4];
#pragma unroll
        for (int c = 0; c < 4; ++c)
            bf[c] = *(const half8*)&W1tc[(((size_t)kt * 16 + wid * 4 + c) * 16 + lr) * 32 + lg * 8];
        half8 a0 = *(const half8*)&xs[lr][kt * 32 + lg * 8];
        half8 a1 = *(const half8*)&xs[16 + lr][kt * 32 + lg * 8];
#pragma unroll
        for (int c = 0; c < 4; ++c) {
            acc1[0][c] = __builtin_amdgcn_mfma_f32_16x16x32_f16(a0, bf[c], acc1[0][c], 0, 0, 0);
            acc1[1][c] = __builtin_amdgcn_mfma_f32_16x16x32_f16(a1, bf[c], acc1[1][c], 0, 0, 0);
        }
    }

#pragma unroll
    for (int rt = 0; rt < 2; ++rt)
#pragma unroll
        for (int c = 0; c < 4; ++c)
#pragma unroll
            for (int r = 0; r < 4; ++r) {
                float v = fmaxf(acc1[rt][c][r], 0.f);
                hmid[rt * 16 + lg * 4 + r][wid * 64 + c * 16 + lr] = (_Float16)v;
            }
    __syncthreads();

    const int rt = wid >> 1, ct2 = (wid & 1) * 2;
    floatx4 acc2[2] = {(floatx4){0,0,0,0}, (floatx4){0,0,0,0}};
#pragma unroll
    for (int kt = 0; kt < 8; ++kt) {
        half8 a = *(const half8*)&hmid[rt * 16 + lr][kt * 32 + lg * 8];
#pragma unroll
        for (int q = 0; q < 2; ++q) {
            half8 b = *(const half8*)&W2tc[((size_t)(kt * 4 + ct2 + q) * 16 + lr) * 32 + lg * 8];
            acc2[q] = __builtin_amdgcn_mfma_f32_16x16x32_f16(a, b, acc2[q], 0, 0, 0);
        }
    }
#pragma unroll
    for (int q = 0; q < 2; ++q) {
        int col = (ct2 + q) * 16 + lr;
        float bb = b2[col];
#pragma unroll
        for (int r = 0; r < 4; ++r) {
            int row = r0blk + rt * 16 + lg * 4 + r;
            float di = dinv[row];
            g0h[(size_t)row * 64 + col] = (_Float16)(di * (acc2[q][r] + bb));
        }
    }
}

// ---------------- graph preprocessing (bucketed CSR, XCD-range partitioned) ----------------
__global__ void init_counts_kernel(int* __restrict__ counts, int* __restrict__ count2, int n) {
    int i = blockIdx.x * blockDim.x + threadIdx.x;
    if (i < 4 * n) count2[i] = 0;
    if (i < n) counts[i] = 1;   // self-loop
}

// counts + per-(dst, src-bucket) counts; dst-range partitioned per XCD.
__global__ void count_kernel(const int* __restrict__ srcL, const int* __restrict__ dstL,
                             int* __restrict__ counts, int* __restrict__ count2,
                             int e, int rs, int n, int bsize) {
    const int r = blockIdx.x & 7;
    const int g = blockIdx.x >> 3;
    const int B = gridDim.x >> 3;
    const int lo = r * rs;
    const int hi = min(lo + rs, n);
    for (int i = g * blockDim.x + threadIdx.x; i < e; i += B * blockDim.x) {
        int d = dstL[i];
        if (d >= lo && d < hi) {
            atomicAdd(&counts[d], 1);
            int b = srcL[i] / bsize;
            atomicAdd(&count2[d * 4 + b], 1);
        }
    }
}

// dinv = deg^-1/2 ; A = 0.9/deg
__global__ void dinv_kernel(const int* __restrict__ counts, float* __restrict__ dinv,
                            float* __restrict__ Anode, int n) {
    int i = blockIdx.x * blockDim.x + threadIdx.x;
    if (i < n) {
        float deg = (float)counts[i];
        dinv[i] = 1.0f / sqrtf(deg);
        Anode[i] = 0.9f / deg;
    }
}

__global__ __launch_bounds__(256) void scan_a(const int* __restrict__ counts,
                                              int* __restrict__ rowptr,
                                              int* __restrict__ bsums, int n)
{
    __shared__ int s[256];
    const int t = threadIdx.x;
    const int i = blockIdx.x * 256 + t;
    int v = (i < n) ? (counts[i] - 1) : 0;
    s[t] = v;
    __syncthreads();
    for (int off = 1; off < 256; off <<= 1) {
        int add = (t >= off) ? s[t - off] : 0;
        __syncthreads();
        s[t] += add;
        __syncthreads();
    }
    if (i < n) rowptr[i] = s[t] - v;
    if (t == 255) bsums[blockIdx.x] = s[255];
}

__global__ __launch_bounds__(512) void scan_b(const int* __restrict__ bsums,
                                              int* __restrict__ boff, int nb)
{
    __shared__ int s[512];
    const int t = threadIdx.x;
    int v = (t < nb) ? bsums[t] : 0;
    s[t] = v;
    __syncthreads();
    for (int off = 1; off < 512; off <<= 1) {
        int add = (t >= off) ? s[t - off] : 0;
        __syncthreads();
        s[t] += add;
        __syncthreads();
    }
    if (t < nb) boff[t] = s[t] - v;
}

__global__ __launch_bounds__(256) void scan_c(int* __restrict__ rowptr,
                                              const int* __restrict__ boff, int n)
{
    int i = blockIdx.x * 256 + threadIdx.x;
    if (i < n) rowptr[i] += boff[blockIdx.x];
}

// per-node bucket boundaries + fill cursors
__global__ void bptr_init(const int* __restrict__ rowptr, const int* __restrict__ count2,
                          int* __restrict__ bptr, int* __restrict__ cursor2, int n, int e)
{
    int i = blockIdx.x * blockDim.x + threadIdx.x;
    if (i < n) {
        int base = rowptr[i];
#pragma unroll
        for (int b = 0; b < 4; ++b) {
            bptr[i * 4 + b] = base;
            cursor2[i * 4 + b] = base;
            base += count2[i * 4 + b];
        }
    }
    if (i == 0) bptr[4 * n] = e;
}

__global__ void fill_kernel(const int* __restrict__ srcL, const int* __restrict__ dstL,
                            int* __restrict__ cursor2, int* __restrict__ srcs,
                            int e, int rs, int n, int bsize) {
    const int r = blockIdx.x & 7;
    const int g = blockIdx.x >> 3;
    const int B = gridDim.x >> 3;
    const int lo = r * rs;
    const int hi = min(lo + rs, n);
    for (int i = g * blockDim.x + threadIdx.x; i < e; i += B * blockDim.x) {
        int d = dstL[i];
        if (d >= lo && d < hi) {
            int s = srcL[i];
            int b = s / bsize;
            int pos = atomicAdd(&cursor2[d * 4 + b], 1);
            srcs[pos] = s;
        }
    }
}

// ---------------- APPNP propagation: one src-bucket pass ----------------
// mode 0: accb = sum_b ; mode 1: accb += sum_b ; mode 2: finalize
//   g_new = A*(acc + sum_b + g_self) + 0.1*g0   (f16 partial acc; error ~5e-5
//   after the A=0.9/deg scaling). Predicated 8-wide batch per 32-lane half.
__global__ __launch_bounds__(256) void prop_pass(
    const uint* __restrict__ gu, const uint* __restrict__ g0u,
    uint* __restrict__ accb, const int* __restrict__ bptr,
    const int* __restrict__ srcs, const float* __restrict__ Anode,
    int n, int mode, int bucket)
{
    const int node = (blockIdx.x * blockDim.x + threadIdx.x) >> 6;
    if (node >= n) return;
    const int lane = threadIdx.x & 63;
    const int half_ = lane >> 5;
    const int p = lane & 31;
    int e = bptr[node * 4 + bucket] + half_;
    const int e1 = bptr[node * 4 + bucket + 1];
    float ax = 0.f, ay = 0.f;
    while (e < e1) {
        const int e1m1 = e1 - 1;
        int idx[8], ss[8];
#pragma unroll
        for (int k = 0; k < 8; ++k) {
            idx[k] = e + 2 * k;
            ss[k] = srcs[min(idx[k], e1m1)];
        }
        float2 f[8];
#pragma unroll
        for (int k = 0; k < 8; ++k)
            f[k] = unpack2(gu[(size_t)ss[k] * 32 + p]);
#pragma unroll
        for (int k = 0; k < 8; ++k)
            if (idx[k] < e1) { ax += f[k].x; ay += f[k].y; }
        e += 16;
    }
    ax += __shfl_xor(ax, 32);
    ay += __shfl_xor(ay, 32);
    if (half_ == 1) return;
    const size_t ro = (size_t)node * 32 + p;
    if (mode == 0) {
        accb[ro] = pack2(ax, ay);
    } else if (mode == 1) {
        float2 a0 = unpack2(accb[ro]);
        accb[ro] = pack2(a0.x + ax, a0.y + ay);
    } else {
        float2 a0 = unpack2(accb[ro]);
        const float A = Anode[node];
        float2 self = unpack2(gu[ro]);
        float2 anc  = unpack2(g0u[ro]);
        float ox = A * (a0.x + ax + self.x) + 0.1f * anc.x;
        float oy = A * (a0.y + ay + self.y) + 0.1f * anc.y;
        accb[ro] = pack2(ox, oy);
    }
}

// ---------------- log_softmax over C=64 (g/dinv, fp32 out) ----------------
__global__ __launch_bounds__(256) void logsoftmax_kernel(
    const _Float16* __restrict__ g, const float* __restrict__ dinv,
    float* __restrict__ out, int n)
{
    const int row = (blockIdx.x * blockDim.x + threadIdx.x) >> 6;
    const int lane = threadIdx.x & 63;
    if (row >= n) return;
    float v = (float)g[(size_t)row * 64 + lane] / dinv[row];
    float m = v;
#pragma unroll
    for (int o = 32; o > 0; o >>= 1) m = fmaxf(m, __shfl_xor(m, o));
    float ex = expf(v - m);
    float s = ex;
#pragma unroll
    for (int o = 32; o > 0; o >>= 1) s += __shfl_xor(s, o);
    out[(size_t)row * 64 + lane] = v - m - logf(s);
}

// ---------------- launcher ----------------
extern "C" void kernel_launch(void* const* d_in, const int* in_sizes, int n_in,
                              void* d_out, int out_size, void* d_ws, size_t ws_size,
                              hipStream_t stream)
{
    const float* x  = (const float*)d_in[0];
    const int*   ei = (const int*)d_in[1];
    const float* W1 = (const float*)d_in[2];
    const float* b1 = (const float*)d_in[3];
    const float* W2 = (const float*)d_in[4];
    const float* b2 = (const float*)d_in[5];
    float* out = (float*)d_out;

    const int n = in_sizes[0] / 512;    // 100000
    const int e = in_sizes[1] / 2;      // 3200000
    const int* srcL = ei;
    const int* dstL = ei + e;

    char* wsb = (char*)d_ws;
    size_t off = 0;
    auto alloc = [&](size_t bytes) -> void* {
        void* p = wsb + off;
        off = (off + bytes + 255) & ~(size_t)255;
        return p;
    };
    // ~58 MB total
    _Float16* g0h = (_Float16*)alloc((size_t)n * 64 * 2);     // 12.8 MB
    _Float16* gp0 = (_Float16*)alloc((size_t)n * 64 * 2);     // 12.8 MB
    _Float16* gp1 = (_Float16*)alloc((size_t)n * 64 * 2);     // 12.8 MB
    int*   srcs   = (int*)alloc((size_t)e * 4);               // 12.8 MB
    float* dinv   = (float*)alloc((size_t)n * 4);
    float* Anode  = (float*)alloc((size_t)n * 4);
    int*   counts = (int*)alloc((size_t)n * 4);
    int*   count2 = (int*)alloc((size_t)n * 16);              // 1.6 MB
    int*   rowptr = (int*)alloc((size_t)(n + 1) * 4);
    int*   bptr   = (int*)alloc((size_t)(4 * n + 1) * 4);     // 1.6 MB
    int*   cursor2= (int*)alloc((size_t)n * 16);              // 1.6 MB
    int*   bsums  = (int*)alloc(4096);
    int*   boff   = (int*)alloc(4096);
    _Float16* W1tc = (_Float16*)alloc((size_t)512 * 256 * 2);
    _Float16* W2tc = (_Float16*)alloc((size_t)256 * 64 * 2);

    const int nb  = (n + 255) / 256;       // 391 (< 512 for scan_b)
    const int rs  = (n + 7) / 8;           // 12500 per XCD range
    const int bsize = (n + 3) / 4;         // 25000 per src bucket (3.2 MB of g)

    transpose_w1c<<<(512 * 256 + 255) / 256, 256, 0, stream>>>(W1, W1tc);
    transpose_w2c<<<(256 * 64 + 255) / 256, 256, 0, stream>>>(W2, W2tc);

    init_counts_kernel<<<(4 * n + 255) / 256, 256, 0, stream>>>(counts, count2, n);
    count_kernel<<<1024, 256, 0, stream>>>(srcL, dstL, counts, count2, e, rs, n, bsize);
    dinv_kernel<<<nb, 256, 0, stream>>>(counts, dinv, Anode, n);
    scan_a<<<nb, 256, 0, stream>>>(counts, rowptr, bsums, n);
    scan_b<<<1, 512, 0, stream>>>(bsums, boff, nb);
    scan_c<<<nb, 256, 0, stream>>>(rowptr, boff, n);
    bptr_init<<<nb, 256, 0, stream>>>(rowptr, count2, bptr, cursor2, n, e);
    fill_kernel<<<1024, 256, 0, stream>>>(srcL, dstL, cursor2, srcs, e, rs, n, bsize);

    mlp_kernel<<<n / 32, 256, 0, stream>>>(x, W1tc, b1, W2tc, b2, dinv, g0h, n);

    // ping-pong: g0h -> gp0 -> gp1 -> ... iter9 (odd) lands in gp1
    const int pgrid = (n * 64 + 255) / 256;
    const uint* gin = (const uint*)g0h;
    uint* bufs[2] = {(uint*)gp0, (uint*)gp1};
    for (int it = 0; it < 10; ++it) {
        uint* acc = bufs[it & 1];
        for (int b = 0; b < 4; ++b) {
            int mode = (b == 0) ? 0 : ((b == 3) ? 2 : 1);
            prop_pass<<<pgrid, 256, 0, stream>>>(gin, (const uint*)g0h, acc,
                                                 bptr, srcs, Anode, n, mode, b);
        }
        gin = acc;
    }
    logsoftmax_kernel<<<pgrid, 256, 0, stream>>>((const _Float16*)gin, dinv, out, n);
}